// Round 13
// baseline (67.434 us; speedup 1.0000x reference)
//
#include <hip/hip_runtime.h>
#include <hip/hip_bf16.h>

#define N_NODES 8192
#define DIN     256
#define DOUT    128
#define NHEAD   2
#define CTOT    256          // NHEAD*DOUT, flat channel dim
#define NWORDS  256          // N_NODES/32 bitmask words per row
#define LRELU_A 0.2f
#define CAPN    128          // max degree (Binomial mean 32, sd 5.7; max over 8k rows ~58)
#define LDR     40           // LDS row stride (80B = 5x16B, ds_read_b128 conflict-free)

typedef __attribute__((ext_vector_type(8))) short bf16x8;
typedef __attribute__((ext_vector_type(4))) float f32x4;

__device__ __forceinline__ float bf(unsigned short u) {
    return __uint_as_float((unsigned)u << 16);
}
__device__ __forceinline__ unsigned short f2bf(float f) {
    unsigned u = __float_as_uint(f);
    u = (u + 0x7fffu + ((u >> 16) & 1u)) >> 16;
    return (unsigned short)u;
}
__device__ __forceinline__ unsigned pk(float a, float b) {
    return (unsigned)f2bf(a) | ((unsigned)f2bf(b) << 16);
}

// =============================================================================
// K1: b<512: MFMA GEMM 64x64 tile (2 blocks/CU) + per-tile score partials;
//     [512,2560): clear adj bitmask; b==2560: clear S_all.   (R12-identical)
// =============================================================================
__global__ __launch_bounds__(256) void k_pre(const float* __restrict__ x,
                                             const float* __restrict__ W,
                                             const float* __restrict__ a,
                                             unsigned short* __restrict__ hb16,
                                             float* __restrict__ sp_src,   // [4][8192]
                                             float* __restrict__ sp_dst,   // [4][8192]
                                             float4* __restrict__ adjp,
                                             float4* __restrict__ sallp) {
    __shared__ unsigned short As[64 * LDR];   // 5 KB
    __shared__ unsigned short Bs[64 * LDR];   // 5 KB
    int b = blockIdx.x, t = threadIdx.x;

    if (b == 2560) {                      // clear S_all (256 floats)
        if (t < 64) sallp[t] = make_float4(0.f, 0.f, 0.f, 0.f);
        return;
    }
    if (b >= 512) {                       // clear 8 MB bitmask
        adjp[(b - 512) * 256 + t] = make_float4(0.f, 0.f, 0.f, 0.f);
        return;
    }

    // ---- GEMM tile 64x64 ----
    int bm = (b & 127) * 64;
    int bn = (b >> 7) * 64;
    int wv = t >> 6, lane = t & 63;
    int fr = lane & 15, ksl = lane >> 4;

    f32x4 acc[4] = {};
    for (int k0 = 0; k0 < DIN; k0 += 32) {
        {
            int row = t >> 2, slot = t & 3;
            const float4* srcA = reinterpret_cast<const float4*>(&x[(bm + row) * DIN + k0 + slot * 8]);
            float4 va0 = srcA[0], va1 = srcA[1];
            *reinterpret_cast<uint4*>(&As[row * LDR + slot * 8]) =
                make_uint4(pk(va0.x, va0.y), pk(va0.z, va0.w), pk(va1.x, va1.y), pk(va1.z, va1.w));
            const float4* srcB = reinterpret_cast<const float4*>(&W[(bn + row) * DIN + k0 + slot * 8]);
            float4 vb0 = srcB[0], vb1 = srcB[1];
            *reinterpret_cast<uint4*>(&Bs[row * LDR + slot * 8]) =
                make_uint4(pk(vb0.x, vb0.y), pk(vb0.z, vb0.w), pk(vb1.x, vb1.y), pk(vb1.z, vb1.w));
        }
        __syncthreads();
        bf16x8 af = *reinterpret_cast<const bf16x8*>(&As[(wv * 16 + fr) * LDR + ksl * 8]);
        #pragma unroll
        for (int fn = 0; fn < 4; ++fn) {
            bf16x8 bfr = *reinterpret_cast<const bf16x8*>(&Bs[(fn * 16 + fr) * LDR + ksl * 8]);
            acc[fn] = __builtin_amdgcn_mfma_f32_16x16x32_bf16(af, bfr, acc[fn], 0, 0, 0);
        }
        __syncthreads();
    }

    // ---- epilogue: hb16 write (C/D: col=fr, row=ksl*4+r) ----
    #pragma unroll
    for (int fn = 0; fn < 4; ++fn) {
        int c = bn + fn * 16 + fr;
        int r0 = bm + wv * 16 + ksl * 4;
        #pragma unroll
        for (int r = 0; r < 4; ++r)
            hb16[(size_t)(r0 + r) * CTOT + c] = f2bf(acc[fn][r]);
    }

    // ---- score partials ----
    int head = (bn >= 128);
    int q    = bn >> 6;
    float as[4], ad[4];
    #pragma unroll
    for (int fn = 0; fn < 4; ++fn) {
        int d = (bn & 127) + fn * 16 + fr;
        as[fn] = a[head * 256 + d];
        ad[fn] = a[head * 256 + 128 + d];
    }
    #pragma unroll
    for (int r = 0; r < 4; ++r) {
        float ps = acc[0][r] * as[0] + acc[1][r] * as[1] + acc[2][r] * as[2] + acc[3][r] * as[3];
        float pd = acc[0][r] * ad[0] + acc[1][r] * ad[1] + acc[2][r] * ad[2] + acc[3][r] * ad[3];
        #pragma unroll
        for (int off = 8; off; off >>= 1) {
            ps += __shfl_xor(ps, off);
            pd += __shfl_xor(pd, off);
        }
        if (fr == 0) {
            int row = bm + wv * 16 + ksl * 4 + r;
            sp_src[q * N_NODES + row] = ps;
            sp_dst[q * N_NODES + row] = pd;
        }
    }
}

// =============================================================================
// K2: b<1024: edge scatter; [1024,1056): score reduce; [1056,1568): colsum.
// (R12-identical)
// =============================================================================
__global__ __launch_bounds__(256) void k_mid(const int* __restrict__ ei, int E,
                                             unsigned int* __restrict__ adjw,
                                             const float* __restrict__ sp_src,
                                             const float* __restrict__ sp_dst,
                                             const unsigned short* __restrict__ hb16,
                                             float* __restrict__ s_src,
                                             float* __restrict__ s_dst,
                                             float* __restrict__ S_all) {
    int b = blockIdx.x, t = threadIdx.x;

    if (b < 1024) {                       // edge scatter
        int e = b * 256 + t;
        if (e < E) {
            int src = ei[e];
            int dst = ei[E + e];
            atomicOr(&adjw[(size_t)src * NWORDS + (dst >> 5)], 1u << (dst & 31));
        }
        return;
    }
    if (b < 1056) {                       // score reduce
        int n = (b - 1024) * 256 + t;
        s_src[n]           = sp_src[0 * N_NODES + n] + sp_src[1 * N_NODES + n];
        s_src[N_NODES + n] = sp_src[2 * N_NODES + n] + sp_src[3 * N_NODES + n];
        s_dst[n]           = sp_dst[0 * N_NODES + n] + sp_dst[1 * N_NODES + n];
        s_dst[N_NODES + n] = sp_dst[2 * N_NODES + n] + sp_dst[3 * N_NODES + n];
        return;
    }

    // colsum: 512 blocks x 16 rows, one atomic per thread
    int r0 = (b - 1056) * 16;
    float s = 0.f;
    #pragma unroll
    for (int r = r0; r < r0 + 16; ++r)
        s += bf(hb16[r * CTOT + t]);
    atomicAdd(&S_all[t], s);
}

// =============================================================================
// K3: barrier-free attention — block per row, 4 INDEPENDENT waves.
// Each wave: redundant compaction into its private nbr/ew copy, weights for
// its own head (k = lane, lane+64 -> all lanes busy), in-register Z, gather
// of its 64 owned channels (c = wv*64+lane). Zero __syncthreads().
// =============================================================================
__global__ __launch_bounds__(256) void k_attn(const unsigned int* __restrict__ adjw,
                                              const float* __restrict__ s_src,
                                              const float* __restrict__ s_dst,
                                              const unsigned short* __restrict__ hb16,
                                              const float* __restrict__ S_all,
                                              float* __restrict__ out) {
    __shared__ unsigned short nbr[4][CAPN];   // 1 KB (per-wave private)
    __shared__ float          ewl[4][CAPN];   // 2 KB (per-wave private)

    int i    = blockIdx.x;
    int t    = threadIdx.x;
    int wv   = t >> 6;
    int lane = t & 63;
    int head = wv >> 1;
    int c    = wv * 64 + lane;            // owned output channel

    // --- compaction (redundant per wave; same-wave LDS is in-order) ---
    const uint4 wq = reinterpret_cast<const uint4*>(adjw + (size_t)i * NWORDS)[lane];
    int cnt = __popc(wq.x) + __popc(wq.y) + __popc(wq.z) + __popc(wq.w);
    int inc = cnt;
    #pragma unroll
    for (int off = 1; off < 64; off <<= 1) {
        int v = __shfl_up(inc, off);
        if (lane >= off) inc += v;
    }
    int deg = __shfl(inc, 63);
    int pos = inc - cnt;
    int idb = lane * 128;
    {
        unsigned int w;
        w = wq.x; while (w) { int bb = __ffs(w) - 1; w &= w - 1; if (pos < CAPN) nbr[wv][pos] = (unsigned short)(idb + bb);      ++pos; }
        w = wq.y; while (w) { int bb = __ffs(w) - 1; w &= w - 1; if (pos < CAPN) nbr[wv][pos] = (unsigned short)(idb + 32 + bb); ++pos; }
        w = wq.z; while (w) { int bb = __ffs(w) - 1; w &= w - 1; if (pos < CAPN) nbr[wv][pos] = (unsigned short)(idb + 64 + bb); ++pos; }
        w = wq.w; while (w) { int bb = __ffs(w) - 1; w &= w - 1; if (pos < CAPN) nbr[wv][pos] = (unsigned short)(idb + 96 + bb); ++pos; }
    }
    if (deg > CAPN) deg = CAPN;

    // --- weights for own head (k = lane, lane+64) + in-register Z ---
    float ssh = s_src[head * N_NODES + i];
    const float* sdh = s_dst + head * N_NODES;
    float z = 0.f;
    for (int k = lane; k < deg; k += 64) {
        int j = nbr[wv][k];
        float v = ssh + sdh[j];
        float e = v > 0.f ? v : LRELU_A * v;
        float w = expf(e) - 1.f;
        ewl[wv][k] = w;
        z += w;
    }
    #pragma unroll
    for (int off = 32; off; off >>= 1)
        z += __shfl_xor(z, off);
    float Z = (float)N_NODES + z;

    // --- gather: broadcast nbr/ew reads, ILP-8 on 2B channel loads ---
    float acc = 0.f;
    int k = 0;
    for (; k + 8 <= deg; k += 8) {
        int j0 = nbr[wv][k+0], j1 = nbr[wv][k+1], j2 = nbr[wv][k+2], j3 = nbr[wv][k+3];
        int j4 = nbr[wv][k+4], j5 = nbr[wv][k+5], j6 = nbr[wv][k+6], j7 = nbr[wv][k+7];
        float w0 = ewl[wv][k+0], w1 = ewl[wv][k+1], w2 = ewl[wv][k+2], w3 = ewl[wv][k+3];
        float w4 = ewl[wv][k+4], w5 = ewl[wv][k+5], w6 = ewl[wv][k+6], w7 = ewl[wv][k+7];
        float v0 = bf(hb16[j0 * CTOT + c]);
        float v1 = bf(hb16[j1 * CTOT + c]);
        float v2 = bf(hb16[j2 * CTOT + c]);
        float v3 = bf(hb16[j3 * CTOT + c]);
        float v4 = bf(hb16[j4 * CTOT + c]);
        float v5 = bf(hb16[j5 * CTOT + c]);
        float v6 = bf(hb16[j6 * CTOT + c]);
        float v7 = bf(hb16[j7 * CTOT + c]);
        acc = fmaf(w0, v0, acc); acc = fmaf(w1, v1, acc);
        acc = fmaf(w2, v2, acc); acc = fmaf(w3, v3, acc);
        acc = fmaf(w4, v4, acc); acc = fmaf(w5, v5, acc);
        acc = fmaf(w6, v6, acc); acc = fmaf(w7, v7, acc);
    }
    for (; k + 4 <= deg; k += 4) {
        int j0 = nbr[wv][k], j1 = nbr[wv][k+1], j2 = nbr[wv][k+2], j3 = nbr[wv][k+3];
        float w0 = ewl[wv][k], w1 = ewl[wv][k+1], w2 = ewl[wv][k+2], w3 = ewl[wv][k+3];
        float v0 = bf(hb16[j0 * CTOT + c]);
        float v1 = bf(hb16[j1 * CTOT + c]);
        float v2 = bf(hb16[j2 * CTOT + c]);
        float v3 = bf(hb16[j3 * CTOT + c]);
        acc = fmaf(w0, v0, acc); acc = fmaf(w1, v1, acc);
        acc = fmaf(w2, v2, acc); acc = fmaf(w3, v3, acc);
    }
    for (; k < deg; ++k)
        acc = fmaf(ewl[wv][k], bf(hb16[nbr[wv][k] * CTOT + c]), acc);

    float o = (S_all[c] + acc) / Z;
    o = o > 0.f ? o : expm1f(o);           // ELU (alpha=1)
    out[i * CTOT + c] = o;
}

// ---------------- launch ------------------------------------------------------
extern "C" void kernel_launch(void* const* d_in, const int* in_sizes, int n_in,
                              void* d_out, int out_size, void* d_ws, size_t ws_size,
                              hipStream_t stream) {
    const float* x  = (const float*)d_in[0];
    const float* W  = (const float*)d_in[1];
    const float* a  = (const float*)d_in[2];
    const int*   ei = (const int*)d_in[3];
    int E = in_sizes[3] / 2;
    float* out = (float*)d_out;

    char* ws = (char*)d_ws;
    size_t off = 0;
    auto alloc = [&](size_t bytes) { char* p = ws + off; off += (bytes + 255) & ~(size_t)255; return p; };
    unsigned int*   adjw   = (unsigned int*)  alloc((size_t)N_NODES * NWORDS * 4); // 8 MB
    float*          S_all  = (float*)         alloc(CTOT * 4);
    float*          s_src  = (float*)         alloc((size_t)NHEAD * N_NODES * 4);
    float*          s_dst  = (float*)         alloc((size_t)NHEAD * N_NODES * 4);
    unsigned short* hb16   = (unsigned short*)alloc((size_t)N_NODES * CTOT * 2);  // 4 MB
    float*          sp_src = (float*)         alloc((size_t)4 * N_NODES * 4);     // 128 KB
    float*          sp_dst = (float*)         alloc((size_t)4 * N_NODES * 4);     // 128 KB

    k_pre<<<2561, 256, 0, stream>>>(x, W, a, hb16, sp_src, sp_dst, (float4*)adjw, (float4*)S_all);
    k_mid<<<1568, 256, 0, stream>>>(ei, E, adjw, sp_src, sp_dst, hb16, s_src, s_dst, S_all);
    k_attn<<<N_NODES, 256, 0, stream>>>(adjw, s_src, s_dst, hb16, S_all, out);
}

// Round 14
// 64.124 us; speedup vs baseline: 1.0516x; 1.0516x over previous
//
#include <hip/hip_runtime.h>
#include <hip/hip_bf16.h>

#define N_NODES 8192
#define DIN     256
#define DOUT    128
#define NHEAD   2
#define CTOT    256          // NHEAD*DOUT, flat channel dim
#define NWORDS  256          // N_NODES/32 bitmask words per row
#define LRELU_A 0.2f
#define CAPN    128          // max degree (Binomial mean 32, sd 5.7; max over 8k rows ~58)

typedef __attribute__((ext_vector_type(8))) short bf16x8;
typedef __attribute__((ext_vector_type(4))) float f32x4;

__device__ __forceinline__ float bf(unsigned short u) {
    return __uint_as_float((unsigned)u << 16);
}
__device__ __forceinline__ float bflo(unsigned u) { return __uint_as_float(u << 16); }
__device__ __forceinline__ float bfhi(unsigned u) { return __uint_as_float(u & 0xffff0000u); }
__device__ __forceinline__ unsigned short f2bf(float f) {
    unsigned u = __float_as_uint(f);
    u = (u + 0x7fffu + ((u >> 16) & 1u)) >> 16;
    return (unsigned short)u;
}
__device__ __forceinline__ unsigned pk(float a, float b) {
    return (unsigned)f2bf(a) | ((unsigned)f2bf(b) << 16);
}

// =============================================================================
// K1: b<512: MFMA GEMM 64x64 tile, WHOLE-K staging (2 barriers total).
//     LDS [64][256] bf16 per matrix (64KB), 16B-slot XOR swizzle
//     (slot' = slot ^ (row&7)) -> conflict-free ds_read_b128.
//     [512,2560): clear adj bitmask; b==2560: clear S_all.
// =============================================================================
__global__ __launch_bounds__(256) void k_pre(const float* __restrict__ x,
                                             const float* __restrict__ W,
                                             const float* __restrict__ a,
                                             unsigned short* __restrict__ hb16,
                                             float* __restrict__ sp_src,   // [4][8192]
                                             float* __restrict__ sp_dst,   // [4][8192]
                                             float4* __restrict__ adjp,
                                             float4* __restrict__ sallp) {
    __shared__ unsigned short As[64 * 256];   // 32 KB
    __shared__ unsigned short Bs[64 * 256];   // 32 KB
    int b = blockIdx.x, t = threadIdx.x;

    if (b == 2560) {                      // clear S_all (256 floats)
        if (t < 64) sallp[t] = make_float4(0.f, 0.f, 0.f, 0.f);
        return;
    }
    if (b >= 512) {                       // clear 8 MB bitmask
        adjp[(b - 512) * 256 + t] = make_float4(0.f, 0.f, 0.f, 0.f);
        return;
    }

    // ---- GEMM tile 64x64, K = 256 staged once ----
    int bm = (b & 127) * 64;
    int bn = (b >> 7) * 64;
    int wv = t >> 6, lane = t & 63;
    int fr = lane & 15, ksl = lane >> 4;

    // stage: iter i covers one 64-row x 4-float slice; wave covers one row.
    // flat float idx f = (i*256 + t)*4 -> row = f>>8, k = f&255.
    #pragma unroll
    for (int i = 0; i < 16; ++i) {
        int idx = i * 256 + t;
        int row = idx >> 6;               // 0..63
        int kq  = (idx & 63) * 4;         // k = kq..kq+3
        float4 v = *reinterpret_cast<const float4*>(&x[(bm + row) * DIN + kq]);
        int slot = kq >> 3, half = (kq >> 2) & 1;
        *reinterpret_cast<uint2*>(&As[row * 256 + ((slot ^ (row & 7)) << 3) + half * 4]) =
            make_uint2(pk(v.x, v.y), pk(v.z, v.w));
    }
    #pragma unroll
    for (int i = 0; i < 16; ++i) {
        int idx = i * 256 + t;
        int row = idx >> 6;
        int kq  = (idx & 63) * 4;
        float4 v = *reinterpret_cast<const float4*>(&W[(bn + row) * DIN + kq]);
        int slot = kq >> 3, half = (kq >> 2) & 1;
        *reinterpret_cast<uint2*>(&Bs[row * 256 + ((slot ^ (row & 7)) << 3) + half * 4]) =
            make_uint2(pk(v.x, v.y), pk(v.z, v.w));
    }
    __syncthreads();

    f32x4 acc[4] = {};
    #pragma unroll
    for (int ch = 0; ch < 8; ++ch) {
        int s = ch * 4 + ksl;
        int ra = wv * 16 + fr;
        bf16x8 af = *reinterpret_cast<const bf16x8*>(&As[ra * 256 + ((s ^ (ra & 7)) << 3)]);
        #pragma unroll
        for (int fn = 0; fn < 4; ++fn) {
            int rb = fn * 16 + fr;
            bf16x8 bfr = *reinterpret_cast<const bf16x8*>(&Bs[rb * 256 + ((s ^ (rb & 7)) << 3)]);
            acc[fn] = __builtin_amdgcn_mfma_f32_16x16x32_bf16(af, bfr, acc[fn], 0, 0, 0);
        }
    }

    // ---- epilogue: hb16 write (C/D: col=fr, row=ksl*4+r) ----
    #pragma unroll
    for (int fn = 0; fn < 4; ++fn) {
        int c = bn + fn * 16 + fr;
        int r0 = bm + wv * 16 + ksl * 4;
        #pragma unroll
        for (int r = 0; r < 4; ++r)
            hb16[(size_t)(r0 + r) * CTOT + c] = f2bf(acc[fn][r]);
    }

    // ---- score partials ----
    int head = (bn >= 128);
    int q    = bn >> 6;
    float as[4], ad[4];
    #pragma unroll
    for (int fn = 0; fn < 4; ++fn) {
        int d = (bn & 127) + fn * 16 + fr;
        as[fn] = a[head * 256 + d];
        ad[fn] = a[head * 256 + 128 + d];
    }
    #pragma unroll
    for (int r = 0; r < 4; ++r) {
        float ps = acc[0][r] * as[0] + acc[1][r] * as[1] + acc[2][r] * as[2] + acc[3][r] * as[3];
        float pd = acc[0][r] * ad[0] + acc[1][r] * ad[1] + acc[2][r] * ad[2] + acc[3][r] * ad[3];
        #pragma unroll
        for (int off = 8; off; off >>= 1) {
            ps += __shfl_xor(ps, off);
            pd += __shfl_xor(pd, off);
        }
        if (fr == 0) {
            int row = bm + wv * 16 + ksl * 4 + r;
            sp_src[q * N_NODES + row] = ps;
            sp_dst[q * N_NODES + row] = pd;
        }
    }
}

// =============================================================================
// K2: b<1024: edge scatter; [1024,1056): score reduce; [1056,1568): colsum.
// (R12-identical)
// =============================================================================
__global__ __launch_bounds__(256) void k_mid(const int* __restrict__ ei, int E,
                                             unsigned int* __restrict__ adjw,
                                             const float* __restrict__ sp_src,
                                             const float* __restrict__ sp_dst,
                                             const unsigned short* __restrict__ hb16,
                                             float* __restrict__ s_src,
                                             float* __restrict__ s_dst,
                                             float* __restrict__ S_all) {
    int b = blockIdx.x, t = threadIdx.x;

    if (b < 1024) {                       // edge scatter
        int e = b * 256 + t;
        if (e < E) {
            int src = ei[e];
            int dst = ei[E + e];
            atomicOr(&adjw[(size_t)src * NWORDS + (dst >> 5)], 1u << (dst & 31));
        }
        return;
    }
    if (b < 1056) {                       // score reduce
        int n = (b - 1024) * 256 + t;
        s_src[n]           = sp_src[0 * N_NODES + n] + sp_src[1 * N_NODES + n];
        s_src[N_NODES + n] = sp_src[2 * N_NODES + n] + sp_src[3 * N_NODES + n];
        s_dst[n]           = sp_dst[0 * N_NODES + n] + sp_dst[1 * N_NODES + n];
        s_dst[N_NODES + n] = sp_dst[2 * N_NODES + n] + sp_dst[3 * N_NODES + n];
        return;
    }

    // colsum: 512 blocks x 16 rows, one atomic per thread
    int r0 = (b - 1056) * 16;
    float s = 0.f;
    #pragma unroll
    for (int r = r0; r < r0 + 16; ++r)
        s += bf(hb16[r * CTOT + t]);
    atomicAdd(&S_all[t], s);
}

// =============================================================================
// K3: attention — block per row; per-wave compaction+weights (R13), then
// VECTOR gather: wave wv takes neighbors k=wv+4n, lane owns 4 channels via
// one uint2 load (full 512B row per wave-request, 4x fewer requests), ILP-8.
// 2 barriers. LDS combine of per-wave float4 partials.
// =============================================================================
__global__ __launch_bounds__(256) void k_attn(const unsigned int* __restrict__ adjw,
                                              const float* __restrict__ s_src,
                                              const float* __restrict__ s_dst,
                                              const unsigned short* __restrict__ hb16,
                                              const float* __restrict__ S_all,
                                              float* __restrict__ out) {
    __shared__ unsigned short nbr[4][CAPN];   // per-wave private copies
    __shared__ float          ewl[4][CAPN];   // waves 0,1: head0; 2,3: head1
    __shared__ float          zr[4];
    __shared__ float4         part[4][64];

    int i    = blockIdx.x;
    int t    = threadIdx.x;
    int wv   = t >> 6;
    int lane = t & 63;
    int head = wv >> 1;

    // --- per-wave redundant compaction (no cross-wave deps) ---
    const uint4 wq = reinterpret_cast<const uint4*>(adjw + (size_t)i * NWORDS)[lane];
    int cnt = __popc(wq.x) + __popc(wq.y) + __popc(wq.z) + __popc(wq.w);
    int inc = cnt;
    #pragma unroll
    for (int off = 1; off < 64; off <<= 1) {
        int v = __shfl_up(inc, off);
        if (lane >= off) inc += v;
    }
    int deg = __shfl(inc, 63);
    int pos = inc - cnt;
    int idb = lane * 128;
    {
        unsigned int w;
        w = wq.x; while (w) { int bb = __ffs(w) - 1; w &= w - 1; if (pos < CAPN) nbr[wv][pos] = (unsigned short)(idb + bb);      ++pos; }
        w = wq.y; while (w) { int bb = __ffs(w) - 1; w &= w - 1; if (pos < CAPN) nbr[wv][pos] = (unsigned short)(idb + 32 + bb); ++pos; }
        w = wq.z; while (w) { int bb = __ffs(w) - 1; w &= w - 1; if (pos < CAPN) nbr[wv][pos] = (unsigned short)(idb + 64 + bb); ++pos; }
        w = wq.w; while (w) { int bb = __ffs(w) - 1; w &= w - 1; if (pos < CAPN) nbr[wv][pos] = (unsigned short)(idb + 96 + bb); ++pos; }
    }
    if (deg > CAPN) deg = CAPN;

    // --- per-wave weights for own head + in-register Z ---
    float ssh = s_src[head * N_NODES + i];
    const float* sdh = s_dst + head * N_NODES;
    float z = 0.f;
    for (int k = lane; k < deg; k += 64) {
        int j = nbr[wv][k];
        float v = ssh + sdh[j];
        float e = v > 0.f ? v : LRELU_A * v;
        float w = expf(e) - 1.f;
        ewl[wv][k] = w;
        z += w;
    }
    #pragma unroll
    for (int off = 32; off; off >>= 1)
        z += __shfl_xor(z, off);
    if (lane == 0) zr[wv] = (float)N_NODES + z;
    __syncthreads();                       // ewl/zr visible to all waves

    // --- vector gather: wave wv -> k = wv+4n; lane owns channels lane*4..+3 ---
    const uint2* hb2 = reinterpret_cast<const uint2*>(hb16);
    bool lo = lane < 32;                   // channels <128 -> head 0
    float4 acc = make_float4(0.f, 0.f, 0.f, 0.f);
    int k = wv;
    for (; k + 28 < deg; k += 32) {
        int   jj[8]; float ww[8]; uint2 hv[8];
        #pragma unroll
        for (int u = 0; u < 8; ++u) {
            int kk = k + u * 4;
            jj[u] = nbr[wv][kk];
            ww[u] = lo ? ewl[0][kk] : ewl[2][kk];
            hv[u] = hb2[jj[u] * 64 + lane];
        }
        #pragma unroll
        for (int u = 0; u < 8; ++u) {
            acc.x = fmaf(ww[u], bflo(hv[u].x), acc.x);
            acc.y = fmaf(ww[u], bfhi(hv[u].x), acc.y);
            acc.z = fmaf(ww[u], bflo(hv[u].y), acc.z);
            acc.w = fmaf(ww[u], bfhi(hv[u].y), acc.w);
        }
    }
    for (; k < deg; k += 4) {
        int j = nbr[wv][k];
        float w = lo ? ewl[0][k] : ewl[2][k];
        uint2 hv = hb2[j * 64 + lane];
        acc.x = fmaf(w, bflo(hv.x), acc.x);
        acc.y = fmaf(w, bfhi(hv.x), acc.y);
        acc.z = fmaf(w, bflo(hv.y), acc.z);
        acc.w = fmaf(w, bfhi(hv.y), acc.w);
    }
    part[wv][lane] = acc;
    __syncthreads();

    if (t < 64) {
        float4 c0 = part[0][t], c1 = part[1][t], c2 = part[2][t], c3 = part[3][t];
        float4 s;
        s.x = c0.x + c1.x + c2.x + c3.x;
        s.y = c0.y + c1.y + c2.y + c3.y;
        s.z = c0.z + c1.z + c2.z + c3.z;
        s.w = c0.w + c1.w + c2.w + c3.w;
        float4 sa = reinterpret_cast<const float4*>(S_all)[t];
        float rz = 1.f / ((t >= 32) ? zr[2] : zr[0]);
        float4 o;
        o.x = (sa.x + s.x) * rz; o.y = (sa.y + s.y) * rz;
        o.z = (sa.z + s.z) * rz; o.w = (sa.w + s.w) * rz;
        o.x = o.x > 0.f ? o.x : expm1f(o.x);
        o.y = o.y > 0.f ? o.y : expm1f(o.y);
        o.z = o.z > 0.f ? o.z : expm1f(o.z);
        o.w = o.w > 0.f ? o.w : expm1f(o.w);
        reinterpret_cast<float4*>(out)[i * 64 + t] = o;
    }
}

// ---------------- launch ------------------------------------------------------
extern "C" void kernel_launch(void* const* d_in, const int* in_sizes, int n_in,
                              void* d_out, int out_size, void* d_ws, size_t ws_size,
                              hipStream_t stream) {
    const float* x  = (const float*)d_in[0];
    const float* W  = (const float*)d_in[1];
    const float* a  = (const float*)d_in[2];
    const int*   ei = (const int*)d_in[3];
    int E = in_sizes[3] / 2;
    float* out = (float*)d_out;

    char* ws = (char*)d_ws;
    size_t off = 0;
    auto alloc = [&](size_t bytes) { char* p = ws + off; off += (bytes + 255) & ~(size_t)255; return p; };
    unsigned int*   adjw   = (unsigned int*)  alloc((size_t)N_NODES * NWORDS * 4); // 8 MB
    float*          S_all  = (float*)         alloc(CTOT * 4);
    float*          s_src  = (float*)         alloc((size_t)NHEAD * N_NODES * 4);
    float*          s_dst  = (float*)         alloc((size_t)NHEAD * N_NODES * 4);
    unsigned short* hb16   = (unsigned short*)alloc((size_t)N_NODES * CTOT * 2);  // 4 MB
    float*          sp_src = (float*)         alloc((size_t)4 * N_NODES * 4);     // 128 KB
    float*          sp_dst = (float*)         alloc((size_t)4 * N_NODES * 4);     // 128 KB

    k_pre<<<2561, 256, 0, stream>>>(x, W, a, hb16, sp_src, sp_dst, (float4*)adjw, (float4*)S_all);
    k_mid<<<1568, 256, 0, stream>>>(ei, E, adjw, sp_src, sp_dst, hb16, s_src, s_dst, S_all);
    k_attn<<<N_NODES, 256, 0, stream>>>(adjw, s_src, s_dst, hb16, S_all, out);
}

// Round 15
// 54.832 us; speedup vs baseline: 1.2298x; 1.1694x over previous
//
#include <hip/hip_runtime.h>
#include <hip/hip_bf16.h>

#define N_NODES 8192
#define DIN     256
#define DOUT    128
#define NHEAD   2
#define CTOT    256          // NHEAD*DOUT, flat channel dim
#define NWORDS  256          // N_NODES/32 bitmask words per row
#define LRELU_A 0.2f
#define CAPN    128          // max degree (Binomial mean 32, sd 5.7; max over 8k rows ~58)

typedef __attribute__((ext_vector_type(8))) short bf16x8;
typedef __attribute__((ext_vector_type(4))) float f32x4;

__device__ __forceinline__ float bf(unsigned short u) {
    return __uint_as_float((unsigned)u << 16);
}
__device__ __forceinline__ float bflo(unsigned u) { return __uint_as_float(u << 16); }
__device__ __forceinline__ float bfhi(unsigned u) { return __uint_as_float(u & 0xffff0000u); }
__device__ __forceinline__ unsigned short f2bf(float f) {
    unsigned u = __float_as_uint(f);
    u = (u + 0x7fffu + ((u >> 16) & 1u)) >> 16;
    return (unsigned short)u;
}
__device__ __forceinline__ unsigned pk(float a, float b) {
    return (unsigned)f2bf(a) | ((unsigned)f2bf(b) << 16);
}

// =============================================================================
// K1: b<512: MFMA GEMM 64x64 tile, whole-K staging (R14) + score partials
//     + NEW: per-block column partials cpart[128][256] for S_all (no atomics).
//     [512,2560): clear adj bitmask.
// =============================================================================
__global__ __launch_bounds__(256) void k_pre(const float* __restrict__ x,
                                             const float* __restrict__ W,
                                             const float* __restrict__ a,
                                             unsigned short* __restrict__ hb16,
                                             float* __restrict__ sp_src,   // [4][8192]
                                             float* __restrict__ sp_dst,   // [4][8192]
                                             float* __restrict__ cpart,    // [128][256]
                                             float4* __restrict__ adjp) {
    __shared__ unsigned short As[64 * 256];   // 32 KB
    __shared__ unsigned short Bs[64 * 256];   // 32 KB
    __shared__ float          cpl[4][64];     // 1 KB
    int b = blockIdx.x, t = threadIdx.x;

    if (b >= 512) {                       // clear 8 MB bitmask
        adjp[(b - 512) * 256 + t] = make_float4(0.f, 0.f, 0.f, 0.f);
        return;
    }

    // ---- GEMM tile 64x64, K = 256 staged once (16B-slot XOR swizzle) ----
    int bmi = b & 127;
    int bm = bmi * 64;
    int bn = (b >> 7) * 64;
    int wv = t >> 6, lane = t & 63;
    int fr = lane & 15, ksl = lane >> 4;

    #pragma unroll
    for (int i = 0; i < 16; ++i) {
        int idx = i * 256 + t;
        int row = idx >> 6;               // 0..63
        int kq  = (idx & 63) * 4;         // k = kq..kq+3
        float4 v = *reinterpret_cast<const float4*>(&x[(bm + row) * DIN + kq]);
        int slot = kq >> 3, half = (kq >> 2) & 1;
        *reinterpret_cast<uint2*>(&As[row * 256 + ((slot ^ (row & 7)) << 3) + half * 4]) =
            make_uint2(pk(v.x, v.y), pk(v.z, v.w));
    }
    #pragma unroll
    for (int i = 0; i < 16; ++i) {
        int idx = i * 256 + t;
        int row = idx >> 6;
        int kq  = (idx & 63) * 4;
        float4 v = *reinterpret_cast<const float4*>(&W[(bn + row) * DIN + kq]);
        int slot = kq >> 3, half = (kq >> 2) & 1;
        *reinterpret_cast<uint2*>(&Bs[row * 256 + ((slot ^ (row & 7)) << 3) + half * 4]) =
            make_uint2(pk(v.x, v.y), pk(v.z, v.w));
    }
    __syncthreads();

    f32x4 acc[4] = {};
    #pragma unroll
    for (int ch = 0; ch < 8; ++ch) {
        int s = ch * 4 + ksl;
        int ra = wv * 16 + fr;
        bf16x8 af = *reinterpret_cast<const bf16x8*>(&As[ra * 256 + ((s ^ (ra & 7)) << 3)]);
        #pragma unroll
        for (int fn = 0; fn < 4; ++fn) {
            int rb = fn * 16 + fr;
            bf16x8 bfr = *reinterpret_cast<const bf16x8*>(&Bs[rb * 256 + ((s ^ (rb & 7)) << 3)]);
            acc[fn] = __builtin_amdgcn_mfma_f32_16x16x32_bf16(af, bfr, acc[fn], 0, 0, 0);
        }
    }

    // ---- epilogue: hb16 write (C/D: col=fr, row=ksl*4+r) ----
    #pragma unroll
    for (int fn = 0; fn < 4; ++fn) {
        int c = bn + fn * 16 + fr;
        int r0 = bm + wv * 16 + ksl * 4;
        #pragma unroll
        for (int r = 0; r < 4; ++r)
            hb16[(size_t)(r0 + r) * CTOT + c] = f2bf(acc[fn][r]);
    }

    // ---- column partials for S_all (fp32, atomic-free) ----
    // per-lane col fn*16+fr: sum 4 rows; shfl over ksl groups -> wave's 16 rows
    #pragma unroll
    for (int fn = 0; fn < 4; ++fn) {
        float s = acc[fn][0] + acc[fn][1] + acc[fn][2] + acc[fn][3];
        s += __shfl_xor(s, 16);
        s += __shfl_xor(s, 32);
        if (ksl == 0) cpl[wv][fn * 16 + fr] = s;
    }
    __syncthreads();
    if (t < 64)
        cpart[bmi * 256 + bn + t] = cpl[0][t] + cpl[1][t] + cpl[2][t] + cpl[3][t];

    // ---- score partials ----
    int head = (bn >= 128);
    int q    = bn >> 6;
    float as[4], ad[4];
    #pragma unroll
    for (int fn = 0; fn < 4; ++fn) {
        int d = (bn & 127) + fn * 16 + fr;
        as[fn] = a[head * 256 + d];
        ad[fn] = a[head * 256 + 128 + d];
    }
    #pragma unroll
    for (int r = 0; r < 4; ++r) {
        float ps = acc[0][r] * as[0] + acc[1][r] * as[1] + acc[2][r] * as[2] + acc[3][r] * as[3];
        float pd = acc[0][r] * ad[0] + acc[1][r] * ad[1] + acc[2][r] * ad[2] + acc[3][r] * ad[3];
        #pragma unroll
        for (int off = 8; off; off >>= 1) {
            ps += __shfl_xor(ps, off);
            pd += __shfl_xor(pd, off);
        }
        if (fr == 0) {
            int row = bm + wv * 16 + ksl * 4 + r;
            sp_src[q * N_NODES + row] = ps;
            sp_dst[q * N_NODES + row] = pd;
        }
    }
}

// =============================================================================
// K2: b<1024: edge scatter (atomicOr dedup);
//     [1024,1056): score-partial reduce; b==1056: S_all = sum of cpart rows
//     (one block, atomic-free, overlapped with scatter).
// =============================================================================
__global__ __launch_bounds__(256) void k_mid(const int* __restrict__ ei, int E,
                                             unsigned int* __restrict__ adjw,
                                             const float* __restrict__ sp_src,
                                             const float* __restrict__ sp_dst,
                                             const float* __restrict__ cpart,
                                             float* __restrict__ s_src,
                                             float* __restrict__ s_dst,
                                             float* __restrict__ S_all) {
    int b = blockIdx.x, t = threadIdx.x;

    if (b < 1024) {                       // edge scatter
        int e = b * 256 + t;
        if (e < E) {
            int src = ei[e];
            int dst = ei[E + e];
            atomicOr(&adjw[(size_t)src * NWORDS + (dst >> 5)], 1u << (dst & 31));
        }
        return;
    }
    if (b < 1056) {                       // score reduce
        int n = (b - 1024) * 256 + t;
        s_src[n]           = sp_src[0 * N_NODES + n] + sp_src[1 * N_NODES + n];
        s_src[N_NODES + n] = sp_src[2 * N_NODES + n] + sp_src[3 * N_NODES + n];
        s_dst[n]           = sp_dst[0 * N_NODES + n] + sp_dst[1 * N_NODES + n];
        s_dst[N_NODES + n] = sp_dst[2 * N_NODES + n] + sp_dst[3 * N_NODES + n];
        return;
    }

    // ---- S_all[t] = sum over 128 row-blocks of cpart (ILP-16) ----
    float s = 0.f;
    #pragma unroll 16
    for (int p = 0; p < 128; ++p)
        s += cpart[p * 256 + t];
    S_all[t] = s;
}

// =============================================================================
// K3: attention (R14-identical) — block per row; per-wave compaction+weights,
// vector gather (wave wv -> k=wv+4n, lane owns 4 channels via uint2), ILP-8.
// =============================================================================
__global__ __launch_bounds__(256) void k_attn(const unsigned int* __restrict__ adjw,
                                              const float* __restrict__ s_src,
                                              const float* __restrict__ s_dst,
                                              const unsigned short* __restrict__ hb16,
                                              const float* __restrict__ S_all,
                                              float* __restrict__ out) {
    __shared__ unsigned short nbr[4][CAPN];   // per-wave private copies
    __shared__ float          ewl[4][CAPN];   // waves 0,1: head0; 2,3: head1
    __shared__ float          zr[4];
    __shared__ float4         part[4][64];

    int i    = blockIdx.x;
    int t    = threadIdx.x;
    int wv   = t >> 6;
    int lane = t & 63;
    int head = wv >> 1;

    // --- per-wave redundant compaction ---
    const uint4 wq = reinterpret_cast<const uint4*>(adjw + (size_t)i * NWORDS)[lane];
    int cnt = __popc(wq.x) + __popc(wq.y) + __popc(wq.z) + __popc(wq.w);
    int inc = cnt;
    #pragma unroll
    for (int off = 1; off < 64; off <<= 1) {
        int v = __shfl_up(inc, off);
        if (lane >= off) inc += v;
    }
    int deg = __shfl(inc, 63);
    int pos = inc - cnt;
    int idb = lane * 128;
    {
        unsigned int w;
        w = wq.x; while (w) { int bb = __ffs(w) - 1; w &= w - 1; if (pos < CAPN) nbr[wv][pos] = (unsigned short)(idb + bb);      ++pos; }
        w = wq.y; while (w) { int bb = __ffs(w) - 1; w &= w - 1; if (pos < CAPN) nbr[wv][pos] = (unsigned short)(idb + 32 + bb); ++pos; }
        w = wq.z; while (w) { int bb = __ffs(w) - 1; w &= w - 1; if (pos < CAPN) nbr[wv][pos] = (unsigned short)(idb + 64 + bb); ++pos; }
        w = wq.w; while (w) { int bb = __ffs(w) - 1; w &= w - 1; if (pos < CAPN) nbr[wv][pos] = (unsigned short)(idb + 96 + bb); ++pos; }
    }
    if (deg > CAPN) deg = CAPN;

    // --- per-wave weights for own head + in-register Z ---
    float ssh = s_src[head * N_NODES + i];
    const float* sdh = s_dst + head * N_NODES;
    float z = 0.f;
    for (int k = lane; k < deg; k += 64) {
        int j = nbr[wv][k];
        float v = ssh + sdh[j];
        float e = v > 0.f ? v : LRELU_A * v;
        float w = expf(e) - 1.f;
        ewl[wv][k] = w;
        z += w;
    }
    #pragma unroll
    for (int off = 32; off; off >>= 1)
        z += __shfl_xor(z, off);
    if (lane == 0) zr[wv] = (float)N_NODES + z;
    __syncthreads();                       // ewl/zr visible to all waves

    // --- vector gather: wave wv -> k = wv+4n; lane owns channels lane*4..+3 ---
    const uint2* hb2 = reinterpret_cast<const uint2*>(hb16);
    bool lo = lane < 32;                   // channels <128 -> head 0
    float4 acc = make_float4(0.f, 0.f, 0.f, 0.f);
    int k = wv;
    for (; k + 28 < deg; k += 32) {
        int   jj[8]; float ww[8]; uint2 hv[8];
        #pragma unroll
        for (int u = 0; u < 8; ++u) {
            int kk = k + u * 4;
            jj[u] = nbr[wv][kk];
            ww[u] = lo ? ewl[0][kk] : ewl[2][kk];
            hv[u] = hb2[jj[u] * 64 + lane];
        }
        #pragma unroll
        for (int u = 0; u < 8; ++u) {
            acc.x = fmaf(ww[u], bflo(hv[u].x), acc.x);
            acc.y = fmaf(ww[u], bfhi(hv[u].x), acc.y);
            acc.z = fmaf(ww[u], bflo(hv[u].y), acc.z);
            acc.w = fmaf(ww[u], bfhi(hv[u].y), acc.w);
        }
    }
    for (; k < deg; k += 4) {
        int j = nbr[wv][k];
        float w = lo ? ewl[0][k] : ewl[2][k];
        uint2 hv = hb2[j * 64 + lane];
        acc.x = fmaf(w, bflo(hv.x), acc.x);
        acc.y = fmaf(w, bfhi(hv.x), acc.y);
        acc.z = fmaf(w, bflo(hv.y), acc.z);
        acc.w = fmaf(w, bfhi(hv.y), acc.w);
    }
    part[wv][lane] = acc;
    __syncthreads();

    if (t < 64) {
        float4 c0 = part[0][t], c1 = part[1][t], c2 = part[2][t], c3 = part[3][t];
        float4 s;
        s.x = c0.x + c1.x + c2.x + c3.x;
        s.y = c0.y + c1.y + c2.y + c3.y;
        s.z = c0.z + c1.z + c2.z + c3.z;
        s.w = c0.w + c1.w + c2.w + c3.w;
        float4 sa = reinterpret_cast<const float4*>(S_all)[t];
        float rz = 1.f / ((t >= 32) ? zr[2] : zr[0]);
        float4 o;
        o.x = (sa.x + s.x) * rz; o.y = (sa.y + s.y) * rz;
        o.z = (sa.z + s.z) * rz; o.w = (sa.w + s.w) * rz;
        o.x = o.x > 0.f ? o.x : expm1f(o.x);
        o.y = o.y > 0.f ? o.y : expm1f(o.y);
        o.z = o.z > 0.f ? o.z : expm1f(o.z);
        o.w = o.w > 0.f ? o.w : expm1f(o.w);
        reinterpret_cast<float4*>(out)[i * 64 + t] = o;
    }
}

// ---------------- launch ------------------------------------------------------
extern "C" void kernel_launch(void* const* d_in, const int* in_sizes, int n_in,
                              void* d_out, int out_size, void* d_ws, size_t ws_size,
                              hipStream_t stream) {
    const float* x  = (const float*)d_in[0];
    const float* W  = (const float*)d_in[1];
    const float* a  = (const float*)d_in[2];
    const int*   ei = (const int*)d_in[3];
    int E = in_sizes[3] / 2;
    float* out = (float*)d_out;

    char* ws = (char*)d_ws;
    size_t off = 0;
    auto alloc = [&](size_t bytes) { char* p = ws + off; off += (bytes + 255) & ~(size_t)255; return p; };
    unsigned int*   adjw   = (unsigned int*)  alloc((size_t)N_NODES * NWORDS * 4); // 8 MB
    float*          S_all  = (float*)         alloc(CTOT * 4);
    float*          s_src  = (float*)         alloc((size_t)NHEAD * N_NODES * 4);
    float*          s_dst  = (float*)         alloc((size_t)NHEAD * N_NODES * 4);
    unsigned short* hb16   = (unsigned short*)alloc((size_t)N_NODES * CTOT * 2);  // 4 MB
    float*          sp_src = (float*)         alloc((size_t)4 * N_NODES * 4);     // 128 KB
    float*          sp_dst = (float*)         alloc((size_t)4 * N_NODES * 4);     // 128 KB
    float*          cpart  = (float*)         alloc((size_t)128 * 256 * 4);       // 128 KB

    k_pre<<<2560, 256, 0, stream>>>(x, W, a, hb16, sp_src, sp_dst, cpart, (float4*)adjw);
    k_mid<<<1057, 256, 0, stream>>>(ei, E, adjw, sp_src, sp_dst, cpart, s_src, s_dst, S_all);
    k_attn<<<N_NODES, 256, 0, stream>>>(adjw, s_src, s_dst, hb16, S_all, out);
}